// Round 1
// baseline (291.882 us; speedup 1.0000x reference)
//
#include <hip/hip_runtime.h>
#include <hip/hip_bf16.h>

// Transposed conv (full conv): out[b,p,q,co] = sum_{kh,kw,ci} in[b,p-kh,q-kw,ci]*K[ci,co,kh,kw]
// B=8 H=W=256 C=64 KH=KW=3, out 8x258x258x64 fp32. bf16 MFMA path.

#define BN 8
#define HH 256
#define WW 256
#define CC 64
#define OH 258
#define OW 258

typedef __bf16 bf16x8 __attribute__((ext_vector_type(8)));
typedef __bf16 bf16x4 __attribute__((ext_vector_type(4)));
typedef float  f32x4  __attribute__((ext_vector_type(4)));

// ws weight layout: wsW[((tap*2+s)*64+co)*32 + c] = K[ci=32s+c][co][kh][kw], tap=kh*3+kw
__global__ void prep_w_kernel(const float* __restrict__ k, __bf16* __restrict__ wsW) {
    int i = blockIdx.x * 256 + threadIdx.x;            // [0, 36864)
    int c  = i & 31;
    int co = (i >> 5) & 63;
    int st = i >> 11;                                  // [0,18)
    int s   = st & 1;
    int tap = st >> 1;
    int kh = tap / 3, kw = tap % 3;
    int ci = s * 32 + c;
    float v = k[ci * 576 + co * 9 + kh * 3 + kw];      // strides: ci=64*9, co=9, kh=3, kw=1
    wsW[i] = (__bf16)v;
}

static __device__ __forceinline__ void async16(const void* g, void* l) {
    __builtin_amdgcn_global_load_lds(
        (const __attribute__((address_space(1))) void*)g,
        (__attribute__((address_space(3))) void*)l, 16, 0, 0);
}

// stage one tap's 8192B of weights (4096 bf16) into LDS via global_load_lds x16B
static __device__ __forceinline__ void stage_w(const __bf16* __restrict__ wsrc,
                                               __bf16* ldst, int tid) {
    int wv = tid >> 6, lane = tid & 63;
#pragma unroll
    for (int q = 0; q < 2; ++q) {
        const __bf16* g = wsrc + (size_t)(q * 256 + wv * 64 + lane) * 8; // 16B/lane
        __bf16* l = ldst + q * 2048 + wv * 512;                          // wave-uniform base
        async16(g, l);
    }
}

__global__ __launch_bounds__(256, 2)
void tconv_kernel(const float* __restrict__ in, const __bf16* __restrict__ wsW,
                  float* __restrict__ out) {
    // LDS: input patch [s=ci/32][pix=18*18][32] bf16 (41472B) + W double buffer (16384B)
    __shared__ __bf16 lds_in[2 * 324 * 32];
    __shared__ __bf16 lds_w[2 * 4096];

    const int tid = threadIdx.x;
    const int b  = blockIdx.z;
    const int p0 = blockIdx.y * 16;
    const int q0 = blockIdx.x * 16;

    // ---- stage input patch 18x18x64 (rows p0-2..p0+15, cols q0-2..q0+15), zero-pad OOB
    {
#pragma unroll 1
        for (int it = tid; it < 324 * 16; it += 256) {
            int pix = it >> 4, c4 = it & 15;
            int r = pix / 18, c = pix - r * 18;
            int ip = p0 - 2 + r, iq = q0 - 2 + c;
            f32x4 v = {0.f, 0.f, 0.f, 0.f};
            if ((unsigned)ip < 256u && (unsigned)iq < 256u)
                v = *(const f32x4*)(in + (((size_t)b * 256 + ip) * 256 + iq) * 64 + c4 * 4);
            bf16x4 w;
            w[0] = (__bf16)v[0]; w[1] = (__bf16)v[1];
            w[2] = (__bf16)v[2]; w[3] = (__bf16)v[3];
            int half = c4 >> 3;
            *(bf16x4*)&lds_in[(half * 324 + pix) * 32 + (c4 & 7) * 4] = w;
        }
    }

    const int wv = tid >> 6, lane = tid & 63;
    const int laneoff = (lane & 15) * 32 + (lane >> 4) * 8;  // A/B fragment lane offset (elems)

    f32x4 acc[4][4] = {};

    stage_w(wsW, lds_w, tid);  // tap 0 -> buf 0

#pragma unroll
    for (int tap = 0; tap < 9; ++tap) {
        __syncthreads();  // drains vmcnt: staged W(tap) + (iter0) input ds_writes visible
        if (tap + 1 < 9)
            stage_w(wsW + (tap + 1) * 4096, lds_w + ((tap + 1) & 1) * 4096, tid);

        const int kh = tap / 3, kw = tap % 3;
        const __bf16* wb = lds_w + (tap & 1) * 4096;

#pragma unroll
        for (int s = 0; s < 2; ++s) {
            bf16x8 bfr[4];
#pragma unroll
            for (int nt = 0; nt < 4; ++nt)
                bfr[nt] = *(const bf16x8*)(wb + s * 2048 + nt * 512 + laneoff);
#pragma unroll
            for (int mt = 0; mt < 4; ++mt) {
                int pixbase = (4 * wv + mt + 2 - kh) * 18 + (2 - kw);
                bf16x8 afr = *(const bf16x8*)(lds_in + s * 10368 + pixbase * 32 + laneoff);
#pragma unroll
                for (int nt = 0; nt < 4; ++nt)
                    acc[mt][nt] = __builtin_amdgcn_mfma_f32_16x16x32_bf16(
                        afr, bfr[nt], acc[mt][nt], 0, 0, 0);
            }
        }
    }

    // ---- epilogue: D layout col(co)=lane&15, row(q)=quad*4+reg
    const int h = lane >> 4, ml = lane & 15;
#pragma unroll
    for (int mt = 0; mt < 4; ++mt) {
        int p = p0 + 4 * wv + mt;
        if (p < OH) {
            int qb = q0 + 4 * h;
#pragma unroll
            for (int nt = 0; nt < 4; ++nt) {
                float* op = out + (((size_t)b * OH + p) * OW + qb) * 64 + nt * 16 + ml;
#pragma unroll
                for (int r = 0; r < 4; ++r)
                    if (qb + r < OW) op[(size_t)r * 64] = acc[mt][nt][r];
            }
        }
    }
}

extern "C" void kernel_launch(void* const* d_in, const int* in_sizes, int n_in,
                              void* d_out, int out_size, void* d_ws, size_t ws_size,
                              hipStream_t stream) {
    (void)in_sizes; (void)n_in; (void)out_size; (void)ws_size;
    const float* in   = (const float*)d_in[0];
    const float* kern = (const float*)d_in[1];
    float* out = (float*)d_out;
    __bf16* wsW = (__bf16*)d_ws;   // 36864 bf16 = 73728 B

    prep_w_kernel<<<144, 256, 0, stream>>>(kern, wsW);
    dim3 grid(17, 17, 8);
    tconv_kernel<<<grid, 256, 0, stream>>>(in, wsW, out);
}

// Round 2
// 278.672 us; speedup vs baseline: 1.0474x; 1.0474x over previous
//
#include <hip/hip_runtime.h>
#include <hip/hip_bf16.h>

// Transposed conv (full conv): out[b,p,q,co] = sum_{kh,kw,ci} in[b,p-kh,q-kw,ci]*K[ci,co,kh,kw]
// B=8 H=W=256 C=64, out 8x258x258x64 fp32. bf16 MFMA path.
//
// R1 design: 512-thr block, 32x16 output tile. Input patch 34x18x64 bf16 in LDS
// (XOR-swizzled 16B granules -> conflict-free ds_read_b128). Weights pre-swizzled
// to fragment order in d_ws; B-fragments read straight from global (73.7KB, hot in
// L1/L2, shared by all blocks) -> only ONE barrier per block, no weight staging.

#define OH 258
#define OW 258

typedef __bf16 bf16x8 __attribute__((ext_vector_type(8)));
typedef float  f32x4  __attribute__((ext_vector_type(4)));

// ws layout: wsW[((tap*2+s)*64+co)*32 + c] = K[ci=32s+c][co][kh][kw], tap=kh*3+kw
// => fragment (tap,s,nt) is a contiguous 1KB block; lane (ml,h) reads ml*32+h*8.
__global__ void prep_w_kernel(const float* __restrict__ k, __bf16* __restrict__ wsW) {
    int i = blockIdx.x * 256 + threadIdx.x;            // [0, 36864)
    int c  = i & 31;
    int co = (i >> 5) & 63;
    int st = i >> 11;                                  // [0,18)
    int s   = st & 1;
    int tap = st >> 1;
    int kh = tap / 3, kw = tap % 3;
    float v = k[(s * 32 + c) * 576 + co * 9 + kh * 3 + kw];
    wsW[i] = (__bf16)v;
}

__global__ __launch_bounds__(512, 4)
void tconv_kernel(const float* __restrict__ in, const __bf16* __restrict__ wsW,
                  float* __restrict__ out) {
    // input patch [pix=34*18][64ci] bf16, 16B granules XOR-swizzled by pix&7
    __shared__ __bf16 lds_in[612 * 64];   // 78336 B -> 2 blocks/CU

    const int tid = threadIdx.x;
    const int b  = blockIdx.z;
    const int p0 = blockIdx.y * 32;
    const int q0 = blockIdx.x * 16;

    // ---- stage input patch rows p0-2..p0+31, cols q0-2..q0+15; zero-pad OOB
    #pragma unroll 1
    for (int it = tid; it < 612 * 8; it += 512) {
        int pix = it >> 3, c8 = it & 7;                // granule = 8 ci = 16B bf16
        int r = pix / 18, c = pix - r * 18;
        int ip = p0 - 2 + r, iq = q0 - 2 + c;
        f32x4 v0 = {0.f,0.f,0.f,0.f}, v1 = {0.f,0.f,0.f,0.f};
        if ((unsigned)ip < 256u && (unsigned)iq < 256u) {
            const float* g = in + (((size_t)b * 256 + ip) * 256 + iq) * 64 + c8 * 8;
            v0 = *(const f32x4*)g;
            v1 = *(const f32x4*)(g + 4);
        }
        bf16x8 w;
        w[0]=(__bf16)v0[0]; w[1]=(__bf16)v0[1]; w[2]=(__bf16)v0[2]; w[3]=(__bf16)v0[3];
        w[4]=(__bf16)v1[0]; w[5]=(__bf16)v1[1]; w[6]=(__bf16)v1[2]; w[7]=(__bf16)v1[3];
        *(bf16x8*)&lds_in[pix * 64 + (c8 ^ (pix & 7)) * 8] = w;
    }
    __syncthreads();   // the ONLY barrier

    const int wv = tid >> 6, lane = tid & 63;
    const int ml = lane & 15, h = lane >> 4;           // A: m=ml; B: n=ml; k-quad=h
    const int woff = ml * 32 + h * 8;                  // B-frag lane offset (elems)

    f32x4 acc[4][4] = {};   // mt = output row within wave's 4; nt = co/16

    #pragma unroll 1
    for (int tap = 0; tap < 9; ++tap) {
        const int kh = tap / 3, kw = tap - kh * 3;
        const __bf16* wt = wsW + tap * 4096;
        #pragma unroll
        for (int s = 0; s < 2; ++s) {
            bf16x8 bfr[4];
            #pragma unroll
            for (int nt = 0; nt < 4; ++nt)
                bfr[nt] = *(const bf16x8*)(wt + s * 2048 + nt * 512 + woff);
            const int j = s * 4 + h;                   // 16B granule index within pixel
            #pragma unroll
            for (int mt = 0; mt < 4; ++mt) {
                int row = wv * 4 + mt + 2 - kh;        // patch row
                int pix = row * 18 + (2 - kw) + ml;    // m-tile = one output row (16 q)
                bf16x8 afr = *(const bf16x8*)&lds_in[pix * 64 + ((j ^ (pix & 7)) * 8)];
                #pragma unroll
                for (int nt = 0; nt < 4; ++nt)
                    acc[mt][nt] = __builtin_amdgcn_mfma_f32_16x16x32_bf16(
                        afr, bfr[nt], acc[mt][nt], 0, 0, 0);
            }
        }
    }

    // ---- epilogue: D layout col(co)=ml, row(q within row-tile)=h*4+reg
    #pragma unroll
    for (int mt = 0; mt < 4; ++mt) {
        int p = p0 + wv * 4 + mt;
        if (p < OH) {
            int qb = q0 + h * 4;
            #pragma unroll
            for (int nt = 0; nt < 4; ++nt) {
                float* op = out + (((size_t)b * OH + p) * OW + qb) * 64 + nt * 16 + ml;
                #pragma unroll
                for (int r = 0; r < 4; ++r)
                    if (qb + r < OW) op[(size_t)r * 64] = acc[mt][nt][r];
            }
        }
    }
}

extern "C" void kernel_launch(void* const* d_in, const int* in_sizes, int n_in,
                              void* d_out, int out_size, void* d_ws, size_t ws_size,
                              hipStream_t stream) {
    (void)in_sizes; (void)n_in; (void)out_size; (void)ws_size;
    const float* in   = (const float*)d_in[0];
    const float* kern = (const float*)d_in[1];
    float* out = (float*)d_out;
    __bf16* wsW = (__bf16*)d_ws;   // 36864 bf16 = 73728 B

    prep_w_kernel<<<144, 256, 0, stream>>>(kern, wsW);
    dim3 grid(17, 9, 8);           // q-tiles, p-tiles, batch
    tconv_kernel<<<grid, 512, 0, stream>>>(in, wsW, out);
}